// Round 1
// baseline (123.649 us; speedup 1.0000x reference)
//
#include <hip/hip_runtime.h>

#define NB 16
#define CIN 64
#define CT 69
#define NO 128
#define HH 32
#define WW 32
#define HWSZ 1024
#define OUTC 133

// ---------------------------------------------------------------------------
// Kernel 1: 3x3 conv, edge padding, fp32 VALU. Writes conv_out in-place into
// d_out at the (b, o<128, h, w) slots of the (B,133,32,32) output layout.
// Grid: 16 b * 16 h-pairs * 2 o-halves = 512 blocks, 256 threads.
// Thread: one w column, 2 h rows, 8 consecutive o channels (16 accumulators).
// ---------------------------------------------------------------------------
__global__ __launch_bounds__(256) void conv_kernel(
    const float* __restrict__ x, const float* __restrict__ cw,
    const float* __restrict__ cb, float* __restrict__ out)
{
    int blk   = blockIdx.x;
    int ohalf = blk & 1;
    int hp    = (blk >> 1) & 15;
    int b     = blk >> 5;
    int h0    = hp * 2;
    int w     = threadIdx.x & 31;
    int g     = threadIdx.x >> 5;          // 0..7
    int obase = ohalf * 64 + g * 8;

    float acc[2][8];
#pragma unroll
    for (int r = 0; r < 2; ++r)
#pragma unroll
        for (int j = 0; j < 8; ++j) acc[r][j] = cb[obase + j];

    int wm = w - 1 < 0 ? 0 : w - 1;
    int wp = w + 1 > 31 ? 31 : w + 1;

    for (int ci = 0; ci < CIN; ++ci) {
        const float* xb = x + (((size_t)b * CT + ci) << 10);
        float xv[4][3];
#pragma unroll
        for (int r = 0; r < 4; ++r) {
            int rr = h0 - 1 + r;
            rr = rr < 0 ? 0 : (rr > 31 ? 31 : rr);
            const float* rp = xb + (rr << 5);
            xv[r][0] = rp[wm];
            xv[r][1] = rp[w];
            xv[r][2] = rp[wp];
        }
        const float* wb = cw + ((size_t)obase * CIN + ci) * 9;
#pragma unroll
        for (int j = 0; j < 8; ++j) {
            const float* w9 = wb + (size_t)j * (CIN * 9);
#pragma unroll
            for (int ki = 0; ki < 3; ++ki)
#pragma unroll
                for (int kj = 0; kj < 3; ++kj) {
                    float wv = w9[ki * 3 + kj];
                    acc[0][j] = fmaf(xv[ki][kj],     wv, acc[0][j]);
                    acc[1][j] = fmaf(xv[ki + 1][kj], wv, acc[1][j]);
                }
        }
    }
#pragma unroll
    for (int r = 0; r < 2; ++r)
#pragma unroll
        for (int j = 0; j < 8; ++j)
            out[(((size_t)b * OUTC + obase + j) << 10) + ((h0 + r) << 5) + w] =
                acc[r][j];
}

// ---------------------------------------------------------------------------
// Kernel 2: shape-difference sdw[b,o,h,w] = sum_{ch,k} |win - sk[o,ch,k]|.
// Grid: 1024 blocks * 256 threads; gid>>14 = o-chunk (wave-uniform ->
// LDS broadcast), gid&16383 = pixel (lane-consecutive -> coalesced).
// ---------------------------------------------------------------------------
__global__ __launch_bounds__(256) void sdw_kernel(
    const float* __restrict__ x, const float* __restrict__ sk,
    float* __restrict__ sdw)
{
    __shared__ float lsk[NO * 45];
    for (int i = threadIdx.x; i < NO * 45; i += 256) lsk[i] = sk[i];
    __syncthreads();

    int gid = blockIdx.x * 256 + threadIdx.x;   // 0..262143
    int oc  = gid >> 14;                        // 0..15 (uniform per block)
    int pix = gid & 16383;
    int b   = pix >> 10;
    int hw  = pix & 1023;
    int h   = hw >> 5, w = hw & 31;

    float win[45];
#pragma unroll
    for (int ch = 0; ch < 5; ++ch) {
        const float* xb = x + (((size_t)b * CT + CIN + ch) << 10);
#pragma unroll
        for (int ki = 0; ki < 3; ++ki) {
            int rr = h + ki - 1;
            rr = rr < 0 ? 0 : (rr > 31 ? 31 : rr);
            const float* rp = xb + (rr << 5);
#pragma unroll
            for (int kj = 0; kj < 3; ++kj) {
                int cc = w + kj - 1;
                cc = cc < 0 ? 0 : (cc > 31 ? 31 : cc);
                win[ch * 9 + ki * 3 + kj] = rp[cc];
            }
        }
    }
    // center the first two channels on the k=4 (center tap) value
#pragma unroll
    for (int ch = 0; ch < 2; ++ch) {
        float c = win[ch * 9 + 4];
#pragma unroll
        for (int k = 0; k < 9; ++k) win[ch * 9 + k] -= c;
    }

    int ob = oc * 8;
#pragma unroll
    for (int j = 0; j < 8; ++j) {
        const float* kk = &lsk[(ob + j) * 45];
        float s = 0.f;
#pragma unroll
        for (int q = 0; q < 45; ++q) s += fabsf(win[q] - kk[q]);
        sdw[(((size_t)b * NO + ob + j) << 10) + hw] = s;
    }
}

// ---------------------------------------------------------------------------
// Kernel 3: per-channel BN stats (mean, 1/sqrt(var+eps)) for conv (t=0, read
// from d_out layout) and sdw (t=1). 256 blocks = 2 tensors * 128 channels.
// Double accumulators: E[x^2]-m^2 cancellation for sdw (~40 +/- 5) is exact.
// ---------------------------------------------------------------------------
__global__ __launch_bounds__(256) void stats_kernel(
    const float* __restrict__ convd, const float* __restrict__ sdw,
    float* __restrict__ stats)
{
    int cid = blockIdx.x;      // 0..255
    int t   = cid >> 7;
    int ch  = cid & 127;

    double s = 0.0, s2 = 0.0;
    for (int b = 0; b < NB; ++b) {
        const float* p = (t == 0)
            ? convd + (((size_t)b * OUTC + ch) << 10)
            : sdw   + (((size_t)b * NO   + ch) << 10);
        for (int i = threadIdx.x; i < HWSZ; i += 256) {
            double v = (double)p[i];
            s += v; s2 += v * v;
        }
    }
#pragma unroll
    for (int off = 32; off > 0; off >>= 1) {
        s  += __shfl_down(s, off);
        s2 += __shfl_down(s2, off);
    }
    __shared__ double red[8];
    int wid = threadIdx.x >> 6;
    if ((threadIdx.x & 63) == 0) { red[wid * 2] = s; red[wid * 2 + 1] = s2; }
    __syncthreads();
    if (threadIdx.x == 0) {
        s  = red[0] + red[2] + red[4] + red[6];
        s2 = red[1] + red[3] + red[5] + red[7];
        double n   = 16384.0;
        double m   = s / n;
        double var = s2 / n - m * m;
        stats[cid * 2]     = (float)m;
        stats[cid * 2 + 1] = (float)(1.0 / sqrt(var + 1e-5));
    }
}

// ---------------------------------------------------------------------------
// Kernel 4: out = relu(bn(conv) - relu(bn(sdw))) for o<128 (in-place on
// d_out), passthrough x[:, 64+ (o-128)] for o in 128..132.
// ---------------------------------------------------------------------------
__global__ __launch_bounds__(256) void final_kernel(
    const float* __restrict__ x, const float* __restrict__ sdw,
    const float* __restrict__ stats, float* __restrict__ out)
{
    int idx = blockIdx.x * 256 + threadIdx.x;
    if (idx >= NB * OUTC * HWSZ) return;
    int hw  = idx & 1023;
    int rem = idx >> 10;          // = b*133 + o
    int o   = rem % OUTC;
    int b   = rem / OUTC;
    if (o < NO) {
        float cv = out[idx];
        float sv = sdw[(((size_t)b * NO + o) << 10) + hw];
        float cm = stats[o * 2],       cs = stats[o * 2 + 1];
        float sm = stats[256 + o * 2], ss = stats[256 + o * 2 + 1];
        float mu = (sv - sm) * ss;
        mu = mu > 0.f ? mu : 0.f;
        float v = (cv - cm) * cs - mu;
        out[idx] = v > 0.f ? v : 0.f;
    } else {
        out[idx] = x[(((size_t)b * CT + CIN + (o - NO)) << 10) + hw];
    }
}

extern "C" void kernel_launch(void* const* d_in, const int* in_sizes, int n_in,
                              void* d_out, int out_size, void* d_ws, size_t ws_size,
                              hipStream_t stream)
{
    const float* x  = (const float*)d_in[0];
    const float* cw = (const float*)d_in[1];
    const float* cb = (const float*)d_in[2];
    const float* sk = (const float*)d_in[3];
    float* out   = (float*)d_out;
    float* sdw   = (float*)d_ws;                       // 16*128*1024 floats
    float* stats = sdw + (size_t)NB * NO * HWSZ;       // 512 floats

    conv_kernel <<<512, 256, 0, stream>>>(x, cw, cb, out);
    sdw_kernel  <<<1024, 256, 0, stream>>>(x, sk, sdw);
    stats_kernel<<<256, 256, 0, stream>>>(out, sdw, stats);
    final_kernel<<<8512, 256, 0, stream>>>(x, sdw, stats, out);
}

// Round 2
// 62.796 us; speedup vs baseline: 1.9690x; 1.9690x over previous
//
#include <hip/hip_runtime.h>

typedef __attribute__((ext_vector_type(8))) __bf16 bf16x8;
typedef __attribute__((ext_vector_type(4))) float f32x4;

#define NB 16
#define CIN 64
#define CT 69
#define NO 128
#define HWSZ 1024
#define OUTC 133

// round-to-nearest-even fp32 -> bf16 pair packed into u32 (lo = first)
__device__ __forceinline__ unsigned pack_bf16(float a, float b) {
    unsigned ua = __float_as_uint(a);
    ua += 0x7fffu + ((ua >> 16) & 1u);
    unsigned ub = __float_as_uint(b);
    ub += 0x7fffu + ((ub >> 16) & 1u);
    return (ua >> 16) | (ub & 0xffff0000u);
}

__device__ __forceinline__ void gload16(const void* g, void* l) {
    __builtin_amdgcn_global_load_lds(
        (const __attribute__((address_space(1))) unsigned int*)g,
        (__attribute__((address_space(3))) unsigned int*)l, 16, 0, 0);
}

// ---------------------------------------------------------------------------
// Prep 1: xT[b][h][ byte: w*128 + (ci*2 ^ ((w&7)<<4)) ] bf16, 2 MB.
// Swizzle baked into global layout so conv can global_load_lds linearly and
// ds_read_b128 fragments conflict-free (G21 both-sides-or-neither).
// ---------------------------------------------------------------------------
__global__ __launch_bounds__(256) void xprep_kernel(
    const float* __restrict__ x, unsigned* __restrict__ xT)
{
    int bh = blockIdx.x;            // b*32 + h
    int b = bh >> 5, h = bh & 31;
    int w = threadIdx.x & 31;
    int cp0 = threadIdx.x >> 5;     // 0..7
    const float* xr = x + (((size_t)b * CT) << 10) + h * 32 + w;
    unsigned* dst = xT + (size_t)bh * 1024 + w * 32;
    int sw = (w & 7) << 2;
#pragma unroll
    for (int r = 0; r < 4; ++r) {
        int cp = cp0 + r * 8;       // ci pair index 0..31
        float v0 = xr[(size_t)(2 * cp) << 10];
        float v1 = xr[(size_t)(2 * cp + 1) << 10];
        dst[cp ^ sw] = pack_bf16(v0, v1);
    }
}

// ---------------------------------------------------------------------------
// Prep 2: wT[tap][ byte: o*128 + (ci*2 ^ ((o&7)<<4)) ] bf16, 144 KB.
// ---------------------------------------------------------------------------
__global__ __launch_bounds__(256) void wprep_kernel(
    const float* __restrict__ cw, unsigned* __restrict__ wT)
{
    int tg = blockIdx.x * 256 + threadIdx.x;   // 0..4095
    int o = tg >> 5, cp = tg & 31;
    int sw = (o & 7) << 2;
#pragma unroll
    for (int tap = 0; tap < 9; ++tap) {
        float v0 = cw[((size_t)o * CIN + 2 * cp) * 9 + tap];
        float v1 = cw[((size_t)o * CIN + 2 * cp + 1) * 9 + tap];
        wT[tap * 4096 + o * 32 + (cp ^ sw)] = pack_bf16(v0, v1);
    }
}

// ---------------------------------------------------------------------------
// Conv as 9 accumulated MFMA GEMMs. Block = (b, 2 output rows): M=64 px,
// N=128 o, K=576. 8 waves = 2(ci-half) x 2(row) x 2(o-half); wave tile
// 32px x 64o x 32ci per tap -> 2 A-reads + 4 B-reads + 8 MFMA per tap.
// conv_b omitted: exactly cancelled by the no-affine BN that follows.
// ---------------------------------------------------------------------------
__global__ __launch_bounds__(512) void conv_mfma_kernel(
    const char* __restrict__ xT, const char* __restrict__ wT,
    float* __restrict__ out)
{
    __shared__ __align__(16) char smem[49152];
    char* Xs = smem;                 // 16 KB: pixel p at p*128 + swz(ci)
    char* W0 = smem + 16384;         // 16 KB double buffer
    char* W1 = smem + 32768;

    int bid = blockIdx.x;
    int b = bid >> 4;
    int h0 = (bid & 15) * 2;

    int tid = threadIdx.x;
    int lane = tid & 63;
    int wid = tid >> 6;
    int lo = lane & 15, g = lane >> 4;
    int ks = wid >> 2;          // ci half 0/1
    int mg = (wid >> 1) & 1;    // output row within pair
    int ng = wid & 1;           // o half (64)

    // ---- stage X rows clamp(h0-1+s), s=0..3 (4 KB each) ----
#pragma unroll
    for (int q = 0; q < 2; ++q) {
        int ch = wid * 2 + q;                 // 1 KB chunk 0..15
        int s = ch >> 2;
        int srch = h0 - 1 + s; srch = srch < 0 ? 0 : (srch > 31 ? 31 : srch);
        gload16(xT + ((size_t)(b * 32 + srch)) * 4096 + (ch & 3) * 1024 + lane * 16,
                Xs + ch * 1024);
    }
    // ---- stage W tap 0 ----
#pragma unroll
    for (int q = 0; q < 2; ++q) {
        int ch = wid * 2 + q;
        gload16(wT + ch * 1024 + lane * 16, W0 + ch * 1024);
    }

    // fragment LDS offsets (col-clamp for kj baked in; ks*64 XORs bits 4-6)
    int acol[2][3];
#pragma unroll
    for (int i = 0; i < 2; ++i)
#pragma unroll
        for (int kj = 0; kj < 3; ++kj) {
            int cin = i * 16 + lo + kj - 1;
            cin = cin < 0 ? 0 : (cin > 31 ? 31 : cin);
            acol[i][kj] = cin * 128 + ((ks * 64 + g * 16) ^ ((cin & 7) << 4));
        }
    int boff[4];
#pragma unroll
    for (int n = 0; n < 4; ++n) {
        int o = ng * 64 + n * 16 + lo;
        boff[n] = o * 128 + ((ks * 64 + g * 16) ^ ((o & 7) << 4));
    }

    f32x4 acc[2][4];
#pragma unroll
    for (int i = 0; i < 2; ++i)
#pragma unroll
        for (int n = 0; n < 4; ++n) acc[i][n] = (f32x4){0.f, 0.f, 0.f, 0.f};

    __syncthreads();

#pragma unroll
    for (int tap = 0; tap < 9; ++tap) {
        int ki = tap / 3, kj = tap % 3;
        if (tap < 8) {   // prefetch next W tile into the other buffer
            char* wn = ((tap + 1) & 1) ? W1 : W0;
#pragma unroll
            for (int q = 0; q < 2; ++q) {
                int ch = wid * 2 + q;
                gload16(wT + (size_t)(tap + 1) * 16384 + ch * 1024 + lane * 16,
                        wn + ch * 1024);
            }
        }
        const char* wc = (tap & 1) ? W1 : W0;
        bf16x8 a0 = *(const bf16x8*)(Xs + (mg + ki) * 4096 + acol[0][kj]);
        bf16x8 a1 = *(const bf16x8*)(Xs + (mg + ki) * 4096 + acol[1][kj]);
#pragma unroll
        for (int n = 0; n < 4; ++n) {
            bf16x8 bv = *(const bf16x8*)(wc + boff[n]);
            acc[0][n] = __builtin_amdgcn_mfma_f32_16x16x32_bf16(a0, bv, acc[0][n], 0, 0, 0);
            acc[1][n] = __builtin_amdgcn_mfma_f32_16x16x32_bf16(a1, bv, acc[1][n], 0, 0, 0);
        }
        __syncthreads();
    }

    // ---- epilogue: combine ci-halves via LDS, store NCHW coalesced ----
    float* T = (float*)smem;    // [64 px][stride 129] f32 = 33 KB (buffers dead)
    if (ks == 1) {
#pragma unroll
        for (int i = 0; i < 2; ++i)
#pragma unroll
            for (int n = 0; n < 4; ++n)
#pragma unroll
                for (int r = 0; r < 4; ++r) {
                    int pixel = (mg * 2 + i) * 16 + g * 4 + r;
                    int o = ng * 64 + n * 16 + lo;
                    T[pixel * 129 + o] = acc[i][n][r];
                }
    }
    __syncthreads();
    if (ks == 0) {
#pragma unroll
        for (int i = 0; i < 2; ++i)
#pragma unroll
            for (int n = 0; n < 4; ++n)
#pragma unroll
                for (int r = 0; r < 4; ++r) {
                    int pixel = (mg * 2 + i) * 16 + g * 4 + r;
                    int o = ng * 64 + n * 16 + lo;
                    T[pixel * 129 + o] += acc[i][n][r];
                }
    }
    __syncthreads();
    float* obase = out + (((size_t)b * OUTC) << 10) + h0 * 32;
#pragma unroll
    for (int r = 0; r < 4; ++r) {
        int o = r * 32 + (tid >> 4);
        int pq = tid & 15;
        float4 v;
        v.x = T[(pq * 4 + 0) * 129 + o];
        v.y = T[(pq * 4 + 1) * 129 + o];
        v.z = T[(pq * 4 + 2) * 129 + o];
        v.w = T[(pq * 4 + 3) * 129 + o];
        *(float4*)(obase + ((size_t)o << 10) + pq * 4) = v;
    }
}

// ---------------------------------------------------------------------------
// sdw / stats / final: unchanged from round 1 (verified).
// ---------------------------------------------------------------------------
__global__ __launch_bounds__(256) void sdw_kernel(
    const float* __restrict__ x, const float* __restrict__ sk,
    float* __restrict__ sdw)
{
    __shared__ float lsk[NO * 45];
    for (int i = threadIdx.x; i < NO * 45; i += 256) lsk[i] = sk[i];
    __syncthreads();

    int gid = blockIdx.x * 256 + threadIdx.x;
    int oc  = gid >> 14;
    int pix = gid & 16383;
    int b   = pix >> 10;
    int hw  = pix & 1023;
    int h   = hw >> 5, w = hw & 31;

    float win[45];
#pragma unroll
    for (int ch = 0; ch < 5; ++ch) {
        const float* xb = x + (((size_t)b * CT + CIN + ch) << 10);
#pragma unroll
        for (int ki = 0; ki < 3; ++ki) {
            int rr = h + ki - 1;
            rr = rr < 0 ? 0 : (rr > 31 ? 31 : rr);
            const float* rp = xb + (rr << 5);
#pragma unroll
            for (int kj = 0; kj < 3; ++kj) {
                int cc = w + kj - 1;
                cc = cc < 0 ? 0 : (cc > 31 ? 31 : cc);
                win[ch * 9 + ki * 3 + kj] = rp[cc];
            }
        }
    }
#pragma unroll
    for (int ch = 0; ch < 2; ++ch) {
        float c = win[ch * 9 + 4];
#pragma unroll
        for (int k = 0; k < 9; ++k) win[ch * 9 + k] -= c;
    }

    int ob = oc * 8;
#pragma unroll
    for (int j = 0; j < 8; ++j) {
        const float* kk = &lsk[(ob + j) * 45];
        float s = 0.f;
#pragma unroll
        for (int q = 0; q < 45; ++q) s += fabsf(win[q] - kk[q]);
        sdw[(((size_t)b * NO + ob + j) << 10) + hw] = s;
    }
}

__global__ __launch_bounds__(256) void stats_kernel(
    const float* __restrict__ convd, const float* __restrict__ sdw,
    float* __restrict__ stats)
{
    int cid = blockIdx.x;
    int t   = cid >> 7;
    int ch  = cid & 127;

    double s = 0.0, s2 = 0.0;
    for (int b = 0; b < NB; ++b) {
        const float* p = (t == 0)
            ? convd + (((size_t)b * OUTC + ch) << 10)
            : sdw   + (((size_t)b * NO   + ch) << 10);
        for (int i = threadIdx.x; i < HWSZ; i += 256) {
            double v = (double)p[i];
            s += v; s2 += v * v;
        }
    }
#pragma unroll
    for (int off = 32; off > 0; off >>= 1) {
        s  += __shfl_down(s, off);
        s2 += __shfl_down(s2, off);
    }
    __shared__ double red[8];
    int wid = threadIdx.x >> 6;
    if ((threadIdx.x & 63) == 0) { red[wid * 2] = s; red[wid * 2 + 1] = s2; }
    __syncthreads();
    if (threadIdx.x == 0) {
        s  = red[0] + red[2] + red[4] + red[6];
        s2 = red[1] + red[3] + red[5] + red[7];
        double n   = 16384.0;
        double m   = s / n;
        double var = s2 / n - m * m;
        stats[cid * 2]     = (float)m;
        stats[cid * 2 + 1] = (float)(1.0 / sqrt(var + 1e-5));
    }
}

__global__ __launch_bounds__(256) void final_kernel(
    const float* __restrict__ x, const float* __restrict__ sdw,
    const float* __restrict__ stats, float* __restrict__ out)
{
    int idx = blockIdx.x * 256 + threadIdx.x;
    if (idx >= NB * OUTC * HWSZ) return;
    int hw  = idx & 1023;
    int rem = idx >> 10;
    int o   = rem % OUTC;
    int b   = rem / OUTC;
    if (o < NO) {
        float cv = out[idx];
        float sv = sdw[(((size_t)b * NO + o) << 10) + hw];
        float cm = stats[o * 2],       cs = stats[o * 2 + 1];
        float sm = stats[256 + o * 2], ss = stats[256 + o * 2 + 1];
        float mu = (sv - sm) * ss;
        mu = mu > 0.f ? mu : 0.f;
        float v = (cv - cm) * cs - mu;
        out[idx] = v > 0.f ? v : 0.f;
    } else {
        out[idx] = x[(((size_t)b * CT + CIN + (o - NO)) << 10) + hw];
    }
}

extern "C" void kernel_launch(void* const* d_in, const int* in_sizes, int n_in,
                              void* d_out, int out_size, void* d_ws, size_t ws_size,
                              hipStream_t stream)
{
    const float* x  = (const float*)d_in[0];
    const float* cw = (const float*)d_in[1];
    const float* sk = (const float*)d_in[3];
    float* out   = (float*)d_out;

    float*    sdw   = (float*)d_ws;                               // 8 MB
    float*    stats = sdw + (size_t)NB * NO * HWSZ;               // 2 KB
    unsigned* xTu   = (unsigned*)((char*)d_ws + 0x810000);        // 2 MB
    unsigned* wTu   = (unsigned*)((char*)d_ws + 0xA10000);        // 144 KB

    xprep_kernel<<<512, 256, 0, stream>>>(x, xTu);
    wprep_kernel<<<16, 256, 0, stream>>>(cw, wTu);
    sdw_kernel  <<<1024, 256, 0, stream>>>(x, sk, sdw);
    conv_mfma_kernel<<<256, 512, 0, stream>>>((const char*)xTu, (const char*)wTu, out);
    stats_kernel<<<256, 256, 0, stream>>>(out, sdw, stats);
    final_kernel<<<8512, 256, 0, stream>>>(x, sdw, stats, out);
}